// Round 4
// baseline (183.395 us; speedup 1.0000x reference)
//
#include <hip/hip_runtime.h>
#include <hip/hip_cooperative_groups.h>

namespace cg = cooperative_groups;

// Problem constants (match reference file).
#define BB      4
#define LL      4096
#define DD      8
#define KMAX    64
#define NCODES  256   // 2^D

// ---------------------------------------------------------------------------
// Single cooperative kernel, grid = 256 blocks x 1024 threads (co-resident).
//
// Phase 1 (blocks 0..63): block (b,g) packs batch b's 4096 key sign-codes
// into LDS, then its 16 waves each build the answer row for code c = g*16+w:
// first <=64 ascending matching key indices, left-padded with -1.
// res[B][256][64] int32 lives in d_ws.
//
// grid.sync() (device-scope release/acquire -> res visible across XCDs).
//
// Phase 2 (all blocks): each wave serves 4 query rows; one ballot of the 8
// sign bits per 16-lane group yields the code; each lane copies one int4.
// ---------------------------------------------------------------------------
__global__ void __launch_bounds__(1024)
fused_candidates(const float* __restrict__ query_up,
                 const float* __restrict__ key_up,
                 int* __restrict__ res,
                 int* __restrict__ out) {
    __shared__ int scodes[LL];          // 16 KB
    __shared__ int sbuf[16][KMAX];      // 4 KB

    const int t    = threadIdx.x;
    const int lane = t & 63;
    const int w    = t >> 6;

    if (blockIdx.x < BB * 16) {
        const int b = blockIdx.x >> 4;      // batch
        const int g = blockIdx.x & 15;      // code group (16 codes)

        // --- pack: each thread packs 4 keys (2 float4 loads each) ---
        const float4* kp = reinterpret_cast<const float4*>(key_up + (size_t)b * LL * DD);
#pragma unroll
        for (int j = 0; j < 4; ++j) {
            int k = t + j * 1024;
            float4 a  = kp[k * 2];
            float4 c4 = kp[k * 2 + 1];
            int code = ((int)(a.x  > 0.f))
                     | ((int)(a.y  > 0.f) << 1)
                     | ((int)(a.z  > 0.f) << 2)
                     | ((int)(a.w  > 0.f) << 3)
                     | ((int)(c4.x > 0.f) << 4)
                     | ((int)(c4.y > 0.f) << 5)
                     | ((int)(c4.z > 0.f) << 6)
                     | ((int)(c4.w > 0.f) << 7);
            scodes[k] = code;
        }
        __syncthreads();

        // --- build: wave w handles code c; LDS reads inline (independent,
        // compiler pipelines them; no v[64] register array -> no spill) ---
        const int c = g * 16 + w;
        const unsigned long long prefix = (1ull << lane) - 1ull;
        int found = 0;
#pragma unroll
        for (int i = 0; i < 64; ++i) {
            int  vi = scodes[i * 64 + lane];
            bool m  = (vi == c);
            unsigned long long mask = __ballot(m);
            if (m) {
                int rank = found + (int)__popcll(mask & prefix);
                if (rank < KMAX) sbuf[w][rank] = i * 64 + lane;
            }
            found += (int)__popcll(mask);
        }
        int mcount = found < KMAX ? found : KMAX;
        int pad    = KMAX - mcount;
        int val    = (lane < pad) ? -1 : sbuf[w][lane - pad];
        res[((size_t)b * NCODES + c) * KMAX + lane] = val;
    }

    __threadfence();            // release res to device scope
    cg::this_grid().sync();     // all 256 blocks co-resident (cooperative)

    // --- gather: 262144 threads, one int4 per lane, 4 queries per wave ---
    int gtid = blockIdx.x * 1024 + t;           // 0 .. 256*1024-1
    int wq   = gtid >> 6;                       // wave id: 4 queries per wave
    int myq  = wq * 4 + (lane >> 4);            // this lane's query row
    int b2   = myq >> 12;                       // / L
    float x  = query_up[(size_t)myq * DD + (lane & 7)];
    unsigned long long mask = __ballot(x > 0.f);
    int code = (int)((mask >> ((lane >> 4) << 4)) & 0xffull);
    const int4* src = reinterpret_cast<const int4*>(res + ((size_t)b2 * NCODES + code) * KMAX);
    int4 vv = src[lane & 15];
    reinterpret_cast<int4*>(out)[(size_t)myq * 16 + (lane & 15)] = vv;
}

// ---------------------------------------------------------------------------
extern "C" void kernel_launch(void* const* d_in, const int* in_sizes, int n_in,
                              void* d_out, int out_size, void* d_ws, size_t ws_size,
                              hipStream_t stream) {
    const float* query_up = (const float*)d_in[0];   // [B, L, D] f32
    const float* key_up   = (const float*)d_in[1];   // [B, L, D] f32
    // d_in[2] = head_idx, unused by the reference math.

    int* out = (int*)d_out;        // [B, L, KMAX] int32
    int* res = (int*)d_ws;         // [B][256][64] int32 = 256 KB

    void* args[] = { (void*)&query_up, (void*)&key_up, (void*)&res, (void*)&out };
    hipLaunchCooperativeKernel((const void*)fused_candidates,
                               dim3(256), dim3(1024), args, 0, stream);
}

// Round 5
// 66.780 us; speedup vs baseline: 2.7462x; 2.7462x over previous
//
#include <hip/hip_runtime.h>

// Problem constants (match reference file).
#define BB      4
#define LL      4096
#define DD      8
#define KMAX    64
#define NCODES  256    // 2^D
#define NCHUNK  64     // LL / 64 lanes

__device__ __forceinline__ int pack8(const float4& a, const float4& c4) {
    return ((int)(a.x  > 0.f))
         | ((int)(a.y  > 0.f) << 1)
         | ((int)(a.z  > 0.f) << 2)
         | ((int)(a.w  > 0.f) << 3)
         | ((int)(c4.x > 0.f) << 4)
         | ((int)(c4.y > 0.f) << 5)
         | ((int)(c4.z > 0.f) << 6)
         | ((int)(c4.w > 0.f) << 7);
}

// 64-lane match-any: mask of lanes whose `code` equals this lane's `code`.
__device__ __forceinline__ unsigned long long match8(int code) {
    unsigned long long m = ~0ull;
#pragma unroll
    for (int bit = 0; bit < 8; ++bit) {
        unsigned long long bb = __ballot((code >> bit) & 1);
        m &= ((code >> bit) & 1) ? bb : ~bb;
    }
    return m;
}

// ---------------------------------------------------------------------------
// Single kernel, 64 blocks x 1024 threads, no inter-block dependency.
// Block i serves queries [i*256, i*256+256) (batch b = i>>4).
// Phase 1: pack batch's 4096 key codes -> LDS.
// Phase 2: stable counting sort -> resl[256][64]: per-code first <=64
//          ascending key indices, left-padded with -1.
//   2a. per-chunk per-code counts (ballot match-any, leader-writes, no atomics)
//   2b. per-code exclusive prefix over the 64 chunks + pad base
//   2c. rank-stable scatter into resl
// Phase 3: gather -- 4 threads per query, 16 ints each.
// ---------------------------------------------------------------------------
__global__ void __launch_bounds__(1024)
candidates_onepass(const float* __restrict__ query_up,
                   const float* __restrict__ key_up,
                   int* __restrict__ out) {
    __shared__ int            scodes[LL];                 // 16 KB
    __shared__ unsigned short chpre[NCHUNK * NCODES];     // 32 KB: counts -> excl. prefix
    __shared__ int            basec[NCODES];              //  1 KB: -1-pad base per code
    __shared__ int            resl[NCODES * KMAX];        // 64 KB

    const int t     = threadIdx.x;
    const int lane  = t & 63;
    const int w     = t >> 6;            // wave 0..15
    const int b     = blockIdx.x >> 4;   // batch
    const int qbase = blockIdx.x << 8;   // first (global) query row served

    // --- prefill resl with -1; zero chpre --------------------------------
    {
        int4* r4 = reinterpret_cast<int4*>(resl);
        const int4 neg = make_int4(-1, -1, -1, -1);
#pragma unroll
        for (int j = 0; j < 4; ++j) r4[t + j * 1024] = neg;
        uint2* z = reinterpret_cast<uint2*>(chpre);      // 8192 B-pairs -> 4096 uint2
#pragma unroll
        for (int j = 0; j < 4; ++j) z[t + j * 1024] = make_uint2(0u, 0u);
    }

    // --- phase 1: pack key codes -----------------------------------------
    const float4* kp = reinterpret_cast<const float4*>(key_up + (size_t)b * LL * DD);
#pragma unroll
    for (int j = 0; j < 4; ++j) {
        int k = t + j * 1024;
        float4 a  = kp[k * 2];
        float4 c4 = kp[k * 2 + 1];
        scodes[k] = pack8(a, c4);
    }
    __syncthreads();

    // --- phase 2a: per-chunk counts (wave w owns chunks 4w..4w+3) --------
#pragma unroll
    for (int j = 0; j < 4; ++j) {
        int h = w * 4 + j;
        int c = scodes[h * 64 + lane];
        unsigned long long m = match8(c);
        int rank = (int)__popcll(m & ((1ull << lane) - 1ull));
        if (rank == 0) chpre[h * NCODES + c] = (unsigned short)__popcll(m);
    }
    __syncthreads();

    // --- phase 2b: per-code exclusive prefix over chunks + pad base ------
    if (t < NCODES) {
        int running = 0;
#pragma unroll 8
        for (int h = 0; h < NCHUNK; ++h) {
            int v = chpre[h * NCODES + t];
            chpre[h * NCODES + t] = (unsigned short)running;
            running += v;
        }
        int mc = running < KMAX ? running : KMAX;
        basec[t] = KMAX - mc;                 // leading -1 pads
    }
    __syncthreads();

    // --- phase 2c: rank-stable scatter -----------------------------------
#pragma unroll
    for (int j = 0; j < 4; ++j) {
        int h = w * 4 + j;
        int c = scodes[h * 64 + lane];
        unsigned long long m = match8(c);
        int rank = (int)__popcll(m & ((1ull << lane) - 1ull));
        int pos  = basec[c] + (int)chpre[h * NCODES + c] + rank;
        if (pos < KMAX) resl[c * KMAX + pos] = h * 64 + lane;
    }
    __syncthreads();

    // --- phase 3: gather (4 threads per query, 16 ints each) -------------
    {
        int ql   = t >> 2;                   // 0..255
        int part = t & 3;
        int q    = qbase + ql;               // global query row
        const float4* qp = reinterpret_cast<const float4*>(query_up + (size_t)q * DD);
        float4 a  = qp[0];
        float4 c4 = qp[1];
        int code  = pack8(a, c4);
        const int4* src = reinterpret_cast<const int4*>(resl + code * KMAX + part * 16);
        int4* dst = reinterpret_cast<int4*>(out) + ((size_t)q * 16 + part * 4);
#pragma unroll
        for (int r = 0; r < 4; ++r) dst[r] = src[r];
    }
}

// ---------------------------------------------------------------------------
extern "C" void kernel_launch(void* const* d_in, const int* in_sizes, int n_in,
                              void* d_out, int out_size, void* d_ws, size_t ws_size,
                              hipStream_t stream) {
    const float* query_up = (const float*)d_in[0];   // [B, L, D] f32
    const float* key_up   = (const float*)d_in[1];   // [B, L, D] f32
    // d_in[2] = head_idx, unused by the reference math.

    int* out = (int*)d_out;                          // [B, L, KMAX] int32

    candidates_onepass<<<BB * 16, 1024, 0, stream>>>(query_up, key_up, out);
}